// Round 3
// baseline (106.594 us; speedup 1.0000x reference)
//
#include <hip/hip_runtime.h>
#include <stdint.h>

#define B_DIM 4096
#define C_DIM 32
#define D_DIM 128
#define R_DIM 8
#define BM    128
#define NTHREADS 512

typedef __bf16 bf16x8 __attribute__((ext_vector_type(8)));
typedef float  f32x4  __attribute__((ext_vector_type(4)));

// f32 -> bf16 bits, round-to-nearest-even
__device__ __forceinline__ uint32_t f2bf(float f) {
  uint32_t u = __float_as_uint(f);
  return (u + 0x7FFFu + ((u >> 16) & 1u)) >> 16;
}

// XOR swizzle: row-major [row][256B], flip byte bits 4-6 by row&7.
__device__ __forceinline__ uint32_t swz(uint32_t row, uint32_t colbyte) {
  return row * 256u + (colbyte ^ ((row & 7u) << 4));
}

#if __has_builtin(__builtin_amdgcn_exp2f)
#define EXP2F(x) __builtin_amdgcn_exp2f(x)
#else
#define EXP2F(x) exp2f(x)
#endif
#if __has_builtin(__builtin_amdgcn_rcpf)
#define RCPF(x) __builtin_amdgcn_rcpf(x)
#else
#define RCPF(x) (1.0f / (x))
#endif

// 16B async global->LDS. LDS dest = wave-uniform base + lane*16; global addr per-lane.
__device__ __forceinline__ void load_lds16(const void* g, void* l) {
  __builtin_amdgcn_global_load_lds(
      (const __attribute__((address_space(1))) uint32_t*)g,
      (__attribute__((address_space(3))) uint32_t*)l, 16, 0, 0);
}

// ---- prep 1: W f32 -> bf16, PRE-PERMUTED so linear LDS copy lands swizzled ----
__global__ void prep_w(const float* __restrict__ W, uint32_t* __restrict__ ws) {
  uint32_t t = blockIdx.x * 256u + threadIdx.x;       // 65536 threads, 4B each
  uint32_t L = t * 4u;
  uint32_t o  = (L >> 8) & 127u;
  uint32_t rb = L & 255u;
  uint32_t colbyte = rb ^ ((o & 7u) << 4);            // flips bits 4-6 only; pairs intact
  uint32_t eidx = (L >> 15) * 16384u + o * 128u + (colbyte >> 1);
  float2 w2 = *reinterpret_cast<const float2*>(W + eidx);
  ws[t] = f2bf(w2.x) | (f2bf(w2.y) << 16);
}

// ---- prep 2: fold DynamicTanh params. out layout [c][r][3][128] f32 ----
__global__ void prep_acd(const float* __restrict__ A, const float* __restrict__ C,
                         const float* __restrict__ D, float* __restrict__ o) {
  uint32_t t = blockIdx.x * 256u + threadIdx.x;       // 32768 threads
  uint32_t oo = t & 127u, r = (t >> 7) & 7u, c = t >> 10;
  uint32_t in = (r * 32u + c) * 128u + oo;
  float av = A[in], cv = C[in], dv = D[in];
  uint32_t base = ((c * 8u + r) * 3u) * 128u + oo;
  o[base]       = av * 2.88539008177793f;   // a * 2*log2(e): tanh via exp2
  o[base + 128] = -2.f * cv;
  o[base + 256] = cv + dv;
}

__global__ __launch_bounds__(NTHREADS, 4)
void rot_kernel(const float* __restrict__ src, const float* __restrict__ data,
                const uint8_t* __restrict__ wsw, const float* __restrict__ wacd,
                float* __restrict__ out)
{
  __shared__ __align__(16) unsigned char ldsW[2][32768];   // 64 KB W double-buffer
  __shared__ __align__(16) float ldsAcd[R_DIM * 3 * 128];  // 12 KB folded a/c/d

  const uint32_t tid  = threadIdx.x;
  const uint32_t lane = tid & 63u;
  const uint32_t wid  = tid >> 6;     // wave 0..7, owns rows [wid*16, wid*16+16)
  const uint32_t l15  = lane & 15u;
  const uint32_t lg   = lane >> 4;

  const uint32_t c0     = blockIdx.x & 31u;
  const uint32_t b_base = (blockIdx.x >> 5) * BM;
  const uint32_t rowb   = b_base + wid * 16u;

  // ---- stage W_0 into buf0 (linear dest; pre-permuted source) ----
  {
    const uint8_t* g = wsw + tid * 16u;
    #pragma unroll
    for (int j = 0; j < 4; ++j)
      load_lds16(g + j * 8192u, &ldsW[0][wid * 1024u + (uint32_t)j * 8192u]);
  }
  // ---- stage folded a/c/d for this c0: 12 KB linear ----
  {
    const uint8_t* g = (const uint8_t*)wacd + (uint32_t)c0 * 12288u + tid * 16u;
    load_lds16(g, (uint8_t*)ldsAcd + wid * 1024u);
    if (wid < 4)
      load_lds16(g + 8192u, (uint8_t*)ldsAcd + 8192u + wid * 1024u);
  }

  // ---- x (data) in registers, MFMA C/D fragment layout ----
  float x[8][4];
  #pragma unroll
  for (int q = 0; q < 4; ++q) {
    const float* xr = data + ((size_t)(rowb + lg * 4 + q) * C_DIM + c0) * D_DIM;
    #pragma unroll
    for (int n = 0; n < 8; ++n) x[n][q] = xr[n * 16 + l15];
  }

  // ---- source A-fragments in registers (bf16, converted once) ----
  // frag kt: row = rowb + l15, k = kt*32 + lg*8 .. +8
  bf16x8 af[4];
  {
    const float* sr = src + ((size_t)(rowb + l15) * C_DIM + c0) * D_DIM + lg * 8u;
    #pragma unroll
    for (int kt = 0; kt < 4; ++kt) {
      float4 f0 = *reinterpret_cast<const float4*>(sr + kt * 32);
      float4 f1 = *reinterpret_cast<const float4*>(sr + kt * 32 + 4);
      union { uint32_t u[4]; bf16x8 v; } p;
      p.u[0] = f2bf(f0.x) | (f2bf(f0.y) << 16);
      p.u[1] = f2bf(f0.z) | (f2bf(f0.w) << 16);
      p.u[2] = f2bf(f1.x) | (f2bf(f1.y) << 16);
      p.u[3] = f2bf(f1.z) | (f2bf(f1.w) << 16);
      af[kt] = p.v;
    }
  }

  __syncthreads();   // vmcnt(0) drain: W_0 + acd in LDS

  for (int r = 0; r < R_DIM; ++r) {
    // ---- prefetch W_{r+1} into the other buffer (completes under compute) ----
    if (r < 7) {
      const uint8_t* g = wsw + (uint32_t)(r + 1) * 32768u + tid * 16u;
      unsigned char* lb = ldsW[(r + 1) & 1];
      #pragma unroll
      for (int j = 0; j < 4; ++j)
        load_lds16(g + j * 8192u, &lb[wid * 1024u + (uint32_t)j * 8192u]);
    }

    // ---- V = S @ W_r^T (reads current buffer) ----
    const unsigned char* wb = ldsW[r & 1];
    f32x4 acc[8];
    #pragma unroll
    for (int n = 0; n < 8; ++n) acc[n] = (f32x4){0.f, 0.f, 0.f, 0.f};
    #pragma unroll
    for (int kt = 0; kt < 4; ++kt) {
      const uint32_t kb = (uint32_t)kt * 64u + lg * 16u;
      #pragma unroll
      for (int nh = 0; nh < 8; nh += 4) {       // 4 B-frags in flight, caps VGPR
        bf16x8 bq[4];
        #pragma unroll
        for (int i = 0; i < 4; ++i)
          bq[i] = *reinterpret_cast<const bf16x8*>(&wb[swz((nh + i) * 16 + l15, kb)]);
        #pragma unroll
        for (int i = 0; i < 4; ++i)
          acc[nh + i] = __builtin_amdgcn_mfma_f32_16x16x32_bf16(af[kt], bq[i], acc[nh + i], 0, 0, 0);
      }
    }

    // ---- epilogue: t = tanh(a*v)*c + d;  x -= 2*t*(t.x)/max(||t||,eps)^2 ----
    float s2[4] = {0.f, 0.f, 0.f, 0.f}, tx[4] = {0.f, 0.f, 0.f, 0.f};
    const float* acdr = ldsAcd + r * 384;
    #pragma unroll
    for (int n = 0; n < 8; ++n) {
      float a2  = acdr[n * 16 + l15];          // broadcast ds_read (lg-uniform)
      float m2c = acdr[128 + n * 16 + l15];
      float cdv = acdr[256 + n * 16 + l15];
      #pragma unroll
      for (int q = 0; q < 4; ++q) {
        float e = EXP2F(a2 * acc[n][q]);
        float t = fmaf(m2c, RCPF(e + 1.f), cdv);
        acc[n][q] = t;
        s2[q] = fmaf(t, t, s2[q]);
        tx[q] = fmaf(t, x[n][q], tx[q]);
      }
    }
    #pragma unroll
    for (int m = 1; m <= 8; m <<= 1) {
      #pragma unroll
      for (int q = 0; q < 4; ++q) {
        s2[q] += __shfl_xor(s2[q], m);
        tx[q] += __shfl_xor(tx[q], m);
      }
    }
    float sc[4];
    #pragma unroll
    for (int q = 0; q < 4; ++q)
      sc[q] = -2.f * tx[q] * RCPF(fmaxf(s2[q], 1e-24f));
    #pragma unroll
    for (int n = 0; n < 8; ++n) {
      #pragma unroll
      for (int q = 0; q < 4; ++q)
        x[n][q] = fmaf(sc[q], acc[n][q], x[n][q]);
    }

    __syncthreads();   // vmcnt(0): prefetch complete; all reads of wb done
  }

  // ---- store ----
  #pragma unroll
  for (int q = 0; q < 4; ++q) {
    float* orow = out + ((size_t)(rowb + lg * 4 + q) * C_DIM + c0) * D_DIM;
    #pragma unroll
    for (int n = 0; n < 8; ++n) orow[n * 16 + l15] = x[n][q];
  }
}

extern "C" void kernel_launch(void* const* d_in, const int* in_sizes, int n_in,
                              void* d_out, int out_size, void* d_ws, size_t ws_size,
                              hipStream_t stream) {
  const float* src  = (const float*)d_in[0];
  const float* data = (const float*)d_in[1];
  const float* W    = (const float*)d_in[2];
  const float* Aa   = (const float*)d_in[3];
  const float* Cc   = (const float*)d_in[4];
  const float* Dd   = (const float*)d_in[5];
  float* out = (float*)d_out;

  uint8_t* wsW   = (uint8_t*)d_ws;            // 256 KB pre-permuted bf16 W
  float*   wacd  = (float*)((uint8_t*)d_ws + 262144);  // 384 KB folded a/c/d

  prep_w<<<dim3(256), dim3(256), 0, stream>>>(W, (uint32_t*)wsW);
  prep_acd<<<dim3(128), dim3(256), 0, stream>>>(Aa, Cc, Dd, wacd);

  dim3 grid((B_DIM / BM) * C_DIM);   // 1024 workgroups of 512
  dim3 block(NTHREADS);
  rot_kernel<<<grid, block, 0, stream>>>(src, data, wsW, wacd, out);
}

// Round 4
// 90.384 us; speedup vs baseline: 1.1793x; 1.1793x over previous
//
#include <hip/hip_runtime.h>
#include <stdint.h>

#define B_DIM 4096
#define C_DIM 32
#define D_DIM 128
#define R_DIM 8
#define BM    128
#define NTHREADS 512

typedef __bf16 bf16x8 __attribute__((ext_vector_type(8)));
typedef float  f32x4  __attribute__((ext_vector_type(4)));

// f32 -> bf16 bits, round-to-nearest-even
__device__ __forceinline__ uint32_t f2bf(float f) {
  uint32_t u = __float_as_uint(f);
  return (u + 0x7FFFu + ((u >> 16) & 1u)) >> 16;
}

#if __has_builtin(__builtin_amdgcn_exp2f)
#define EXP2F(x) __builtin_amdgcn_exp2f(x)
#else
#define EXP2F(x) exp2f(x)
#endif
#if __has_builtin(__builtin_amdgcn_rcpf)
#define RCPF(x) __builtin_amdgcn_rcpf(x)
#else
#define RCPF(x) (1.0f / (x))
#endif

// 16B async global->LDS. LDS dest = wave-uniform base + lane*16; global addr per-lane.
__device__ __forceinline__ void load_lds16(const void* g, void* l) {
  __builtin_amdgcn_global_load_lds(
      (const __attribute__((address_space(1))) uint32_t*)g,
      (__attribute__((address_space(3))) uint32_t*)l, 16, 0, 0);
}

// DPP row_ror:N add — 16-lane rotation reduction entirely on the VALU pipe
// (replaces ds_swizzle shuffles; LDS pipe was the measured bottleneck).
template <int CTRL>
__device__ __forceinline__ float ror_add(float v) {
  int r = __builtin_amdgcn_update_dpp(0, __builtin_bit_cast(int, v), CTRL, 0xf, 0xf, true);
  return v + __builtin_bit_cast(float, r);
}
__device__ __forceinline__ float red16(float v) {
  v = ror_add<0x128>(v);   // ROW_ROR:8
  v = ror_add<0x124>(v);   // ROW_ROR:4
  v = ror_add<0x122>(v);   // ROW_ROR:2
  v = ror_add<0x121>(v);   // ROW_ROR:1
  return v;                // all 16 lanes of the row hold the sum
}

// ---- prep 1: W f32 -> bf16, laid out [r][n][kt][lane][8 bf16] so the MFMA
// B-fragment read for (n,kt) is a CONTIGUOUS 1KB block: addr = lane*16 + imm.
// Zero bank conflicts by construction; LDS image = linear copy of ws.
__global__ void prep_w(const float* __restrict__ W, uint32_t* __restrict__ ws) {
  uint32_t t = blockIdx.x * 256u + threadIdx.x;   // 65536 threads, one dword each
  uint32_t c  = t >> 2;           // 16B chunk index
  uint32_t j  = t & 3u;           // dword within chunk -> elements j*2, j*2+1
  uint32_t ln = c & 63u;          // lane
  uint32_t kt = (c >> 6) & 3u;
  uint32_t n  = (c >> 8) & 7u;
  uint32_t r  = c >> 11;
  uint32_t o  = n * 16u + (ln & 15u);           // output col (B col)
  uint32_t k  = kt * 32u + (ln >> 4) * 8u + j * 2u;
  const float2 w2 = *reinterpret_cast<const float2*>(
      W + ((size_t)(r * 128u + o)) * 128u + k);
  ws[t] = f2bf(w2.x) | (f2bf(w2.y) << 16);
}

// ---- prep 2: fold DynamicTanh params. out layout [c][r][3][128] f32 ----
__global__ void prep_acd(const float* __restrict__ A, const float* __restrict__ C,
                         const float* __restrict__ D, float* __restrict__ o) {
  uint32_t t = blockIdx.x * 256u + threadIdx.x;   // 32768 threads
  uint32_t oo = t & 127u, r = (t >> 7) & 7u, c = t >> 10;
  uint32_t in = (r * 32u + c) * 128u + oo;
  float av = A[in], cv = C[in], dv = D[in];
  uint32_t base = ((c * 8u + r) * 3u) * 128u + oo;
  o[base]       = av * 2.88539008177793f;   // a * 2*log2(e): tanh via exp2
  o[base + 128] = -2.f * cv;
  o[base + 256] = cv + dv;
}

__global__ __launch_bounds__(NTHREADS, 4)
void rot_kernel(const float* __restrict__ src, const float* __restrict__ data,
                const uint8_t* __restrict__ wsw, const float* __restrict__ wacd,
                float* __restrict__ out)
{
  __shared__ __align__(16) unsigned char ldsW[65536];      // 2 x 32KB W dbuf
  __shared__ __align__(16) float ldsAcd[R_DIM * 3 * 128];  // 12 KB folded a/c/d

  const uint32_t tid  = threadIdx.x;
  const uint32_t lane = tid & 63u;
  const uint32_t wid  = tid >> 6;     // wave 0..7, owns rows [wid*16, wid*16+16)
  const uint32_t l15  = lane & 15u;
  const uint32_t lg   = lane >> 4;

  const uint32_t c0     = blockIdx.x & 31u;
  const uint32_t b_base = (blockIdx.x >> 5) * BM;
  const uint32_t rowb   = b_base + wid * 16u;

  // ---- stage W_0 into buf0 (linear copy of pre-permuted ws) ----
  {
    const uint8_t* g = wsw + tid * 16u;
    #pragma unroll
    for (int j = 0; j < 4; ++j)
      load_lds16(g + j * 8192u, &ldsW[wid * 1024u + (uint32_t)j * 8192u]);
  }
  // ---- stage folded a/c/d for this c0: 12 KB linear ----
  {
    const uint8_t* g = (const uint8_t*)wacd + (uint32_t)c0 * 12288u + tid * 16u;
    load_lds16(g, (uint8_t*)ldsAcd + wid * 1024u);
    if (wid < 4)
      load_lds16(g + 8192u, (uint8_t*)ldsAcd + 8192u + wid * 1024u);
  }

  // ---- x (data) in registers, MFMA C/D fragment layout; f32x4 over q ----
  f32x4 x[8];
  #pragma unroll
  for (int q = 0; q < 4; ++q) {
    const float* xr = data + ((size_t)(rowb + lg * 4 + q) * C_DIM + c0) * D_DIM;
    #pragma unroll
    for (int n = 0; n < 8; ++n) x[n][q] = xr[n * 16 + l15];
  }

  // ---- source A-fragments in registers (bf16, converted once) ----
  bf16x8 af[4];
  {
    const float* sr = src + ((size_t)(rowb + l15) * C_DIM + c0) * D_DIM + lg * 8u;
    #pragma unroll
    for (int kt = 0; kt < 4; ++kt) {
      float4 f0 = *reinterpret_cast<const float4*>(sr + kt * 32);
      float4 f1 = *reinterpret_cast<const float4*>(sr + kt * 32 + 4);
      union { uint32_t u[4]; bf16x8 v; } p;
      p.u[0] = f2bf(f0.x) | (f2bf(f0.y) << 16);
      p.u[1] = f2bf(f0.z) | (f2bf(f0.w) << 16);
      p.u[2] = f2bf(f1.x) | (f2bf(f1.y) << 16);
      p.u[3] = f2bf(f1.z) | (f2bf(f1.w) << 16);
      af[kt] = p.v;
    }
  }

  __syncthreads();   // vmcnt(0) drain: W_0 + acd in LDS

  for (int r = 0; r < R_DIM; ++r) {
    // ---- prefetch W_{r+1} into the other buffer (completes under compute) ----
    if (r < 7) {
      const uint8_t* g = wsw + (uint32_t)(r + 1) * 32768u + tid * 16u;
      unsigned char* lb = &ldsW[((r + 1) & 1) * 32768u];
      #pragma unroll
      for (int j = 0; j < 4; ++j)
        load_lds16(g + j * 8192u, &lb[wid * 1024u + (uint32_t)j * 8192u]);
    }

    // ---- V = S @ W_r^T; B-frag reads are contiguous lane*16 + imm ----
    const uint32_t rb = (r & 1) * 32768u + lane * 16u;
    f32x4 acc[8];
    #pragma unroll
    for (int n = 0; n < 8; ++n) acc[n] = (f32x4){0.f, 0.f, 0.f, 0.f};
    #pragma unroll
    for (int kt = 0; kt < 4; ++kt) {
      #pragma unroll
      for (int nh = 0; nh < 8; nh += 4) {
        bf16x8 bq[4];
        #pragma unroll
        for (int i = 0; i < 4; ++i)
          bq[i] = *reinterpret_cast<const bf16x8*>(
              &ldsW[rb + (uint32_t)(((nh + i) * 4 + kt) * 1024)]);
        #pragma unroll
        for (int i = 0; i < 4; ++i)
          acc[nh + i] = __builtin_amdgcn_mfma_f32_16x16x32_bf16(af[kt], bq[i], acc[nh + i], 0, 0, 0);
      }
    }

    // ---- epilogue: t = tanh(a*v)*c + d;  x -= 2*t*(t.x)/max(||t||,eps)^2 ----
    // vectorized over q (f32x4 -> v_pk_* ops); exp2/rcp scalar on trans pipe
    f32x4 s2 = {0.f, 0.f, 0.f, 0.f}, tx = {0.f, 0.f, 0.f, 0.f};
    const float* acdr = ldsAcd + r * 384;
    #pragma unroll
    for (int n = 0; n < 8; ++n) {
      float a2  = acdr[n * 16 + l15];          // broadcast ds_read
      float m2c = acdr[128 + n * 16 + l15];
      float cdv = acdr[256 + n * 16 + l15];
      f32x4 z = acc[n] * a2;
      f32x4 ep;
      #pragma unroll
      for (int q = 0; q < 4; ++q) ep[q] = EXP2F(z[q]);
      ep = ep + 1.0f;
      f32x4 pr;
      #pragma unroll
      for (int q = 0; q < 4; ++q) pr[q] = RCPF(ep[q]);
      f32x4 t = pr * m2c + cdv;
      acc[n] = t;
      s2 = s2 + t * t;
      tx = tx + t * x[n];
    }
    #pragma unroll
    for (int q = 0; q < 4; ++q) { s2[q] = red16(s2[q]); tx[q] = red16(tx[q]); }
    f32x4 sc;
    #pragma unroll
    for (int q = 0; q < 4; ++q)
      sc[q] = -2.f * tx[q] * RCPF(fmaxf(s2[q], 1e-24f));  // == -2*dot/max(||t||,eps)^2
    #pragma unroll
    for (int n = 0; n < 8; ++n)
      x[n] = x[n] + sc * acc[n];

    __syncthreads();   // vmcnt(0): prefetch complete; all reads of this buf done
  }

  // ---- store ----
  #pragma unroll
  for (int q = 0; q < 4; ++q) {
    float* orow = out + ((size_t)(rowb + lg * 4 + q) * C_DIM + c0) * D_DIM;
    #pragma unroll
    for (int n = 0; n < 8; ++n) orow[n * 16 + l15] = x[n][q];
  }
}

extern "C" void kernel_launch(void* const* d_in, const int* in_sizes, int n_in,
                              void* d_out, int out_size, void* d_ws, size_t ws_size,
                              hipStream_t stream) {
  const float* src  = (const float*)d_in[0];
  const float* data = (const float*)d_in[1];
  const float* W    = (const float*)d_in[2];
  const float* Aa   = (const float*)d_in[3];
  const float* Cc   = (const float*)d_in[4];
  const float* Dd   = (const float*)d_in[5];
  float* out = (float*)d_out;

  uint8_t* wsW  = (uint8_t*)d_ws;                       // 256 KB bf16 W, frag-ordered
  float*   wacd = (float*)((uint8_t*)d_ws + 262144);    // 384 KB folded a/c/d

  prep_w<<<dim3(256), dim3(256), 0, stream>>>(W, (uint32_t*)wsW);
  prep_acd<<<dim3(128), dim3(256), 0, stream>>>(Aa, Cc, Dd, wacd);

  dim3 grid((B_DIM / BM) * C_DIM);   // 1024 workgroups of 512
  dim3 block(NTHREADS);
  rot_kernel<<<grid, block, 0, stream>>>(src, data, wsW, wacd, out);
}